// Round 9
// baseline (53.265 us; speedup 1.0000x reference)
//
#include <hip/hip_runtime.h>

#define WT_L0 8192
#define WT_NT 128

typedef float f4 __attribute__((ext_vector_type(4)));
typedef float f2 __attribute__((ext_vector_type(2)));

// Quarter-row blocks: block = (row, h), h in 0..3, covering x f4 indices
// G in [512h, 512h+512)  (2048 x-elements each; 4*512 = 2048 f4 = full row).
// LDS floats (8.4 KB):
//   sig1  f2 cells [0,522)   cell j <-> x-f4/pair index  P = 512h-5+j  (0 if OOB)
//   down1 [1048,1562)        ld  <-> global m  = 512h-1+ld
//   sig2  [1568,2090)        ls  <-> global s  = 512h-5+ls
//   down2 [0,258) (reuses sig1; sig1 dead)  ld2 <-> global m2 = 256h-1+ld2
__global__ __launch_bounds__(WT_NT) void wavelet1d_kernel(
    const float* __restrict__ x,
    const float* __restrict__ w0,
    const float* __restrict__ w1,
    const float* __restrict__ w2,
    float* __restrict__ out)
{
    __shared__ float buf[2090];
    const int blk = blockIdx.x;
    const int row = blk >> 2;
    const int h   = blk & 3;
    const int t   = threadIdx.x;
    const float* __restrict__ xr = x + (size_t)row * WT_L0;
    float* __restrict__ outr = out + (size_t)row * 3 * WT_L0;

    float f0[3], f1[5], f2a[7];
    #pragma unroll
    for (int k = 0; k < 3; ++k) f0[k] = w0[k];
    #pragma unroll
    for (int k = 0; k < 5; ++k) f1[k] = w1[k];
    #pragma unroll
    for (int k = 0; k < 7; ++k) f2a[k] = w2[k];

    // composed pool∘conv5 (stride-2, 6 taps) and pool∘conv7 (stride-2, 8 taps)
    const float g0 = 0.5f*f1[0], g1 = 0.5f*(f1[0]+f1[1]), g2 = 0.5f*(f1[1]+f1[2]),
                g3 = 0.5f*(f1[2]+f1[3]), g4 = 0.5f*(f1[3]+f1[4]), g5 = 0.5f*f1[4];
    const float h0 = 0.5f*f2a[0], h1 = 0.5f*(f2a[0]+f2a[1]), h2 = 0.5f*(f2a[1]+f2a[2]),
                h3 = 0.5f*(f2a[2]+f2a[3]), h4 = 0.5f*(f2a[3]+f2a[4]),
                h5 = 0.5f*(f2a[4]+f2a[5]), h6 = 0.5f*(f2a[5]+f2a[6]), h7 = 0.5f*f2a[6];

    f2*    sig1_2 = (f2*)buf;          // cells [0,522)
    float* down1  = buf + 1048;        // [0,514)
    float* sig2   = buf + 1568;        // [0,522)

    // ---- P1: stage sig1 (halo, OOB=0); conv3 -> out0 on own span ----
    {
        const f4* __restrict__ xr4 = (const f4*)xr;
        f4* __restrict__ out0_4 = (f4*)outr;
        const int Gbase = 512 * h - 5;
        for (int j = t; j < 522; j += WT_NT) {
            const int G = Gbase + j;
            f4 v = (G >= 0 && G < 2048) ? xr4[G] : (f4)(0.f);
            f2 s; s.x = 0.5f * (v.x + v.y); s.y = 0.5f * (v.z + v.w);
            sig1_2[j] = s;
            if (j >= 5 && j < 517) {               // own span: G in [512h, 512h+512)
                float lm = (G > 0)    ? xr[4 * G - 1] : 0.f;
                float rp = (G < 2047) ? xr[4 * G + 4] : 0.f;
                f4 o;
                o.x = f0[0]*lm  + f0[1]*v.x + f0[2]*v.y;
                o.y = f0[0]*v.x + f0[1]*v.y + f0[2]*v.z;
                o.z = f0[0]*v.y + f0[1]*v.z + f0[2]*v.w;
                o.w = f0[0]*v.z + f0[1]*v.w + f0[2]*rp;
                __builtin_nontemporal_store(o, &out0_4[G]);
            }
        }
    }
    __syncthreads();

    // ---- P2: down1 = (pool∘conv5)(sig1); sig2 = pool(sig1) ----
    for (int ld = t; ld < 514; ld += WT_NT) {      // m = 512h-1+ld; pairs m-1..m+1 = cells ld+3..ld+5
        f2 a = sig1_2[ld + 3], b = sig1_2[ld + 4], c = sig1_2[ld + 5];
        down1[ld] = g0*a.x + g1*a.y + g2*b.x + g3*b.y + g4*c.x + g5*c.y;
    }
    for (int ls = t; ls < 522; ls += WT_NT) {
        f2 p = sig1_2[ls];
        sig2[ls] = 0.5f * (p.x + p.y);
    }
    __syncthreads();

    // ---- P3: out1 = up2(up2(down1)); down2 = (pool∘conv7)(sig2) -> buf[0,258) ----
    {
        f4* __restrict__ out1_4 = (f4*)(outr + WT_L0);
        #pragma unroll
        for (int c = 0; c < 4; ++c) {
            int lq = t + WT_NT * c;                // 0..511
            int q  = 512 * h + lq;                 // global down1 / out1-f4 index
            int ld = lq + 1;                       // m(ld) = q
            float d0 = down1[ld];
            float dm = (q > 0)    ? down1[ld - 1] : d0;
            float dp = (q < 2047) ? down1[ld + 1] : d0;
            f4 o;
            o.x = 0.375f  * dm + 0.625f * d0;
            o.y = 0.1875f * dm + 0.75f  * d0 + 0.0625f * dp;
            o.z = 0.0625f * dm + 0.75f  * d0 + 0.1875f * dp;
            o.w = 0.625f  * d0 + 0.375f * dp;
            __builtin_nontemporal_store(o, &out1_4[q]);
        }
        float* down2 = buf;                        // sig1 dead
        for (int ld2 = t; ld2 < 258; ld2 += WT_NT) {
            int b = 2 * ld2;                       // sig2 local base: global 2*m2-3
            down2[ld2] = h0*sig2[b]   + h1*sig2[b+1] + h2*sig2[b+2] + h3*sig2[b+3]
                       + h4*sig2[b+4] + h5*sig2[b+5] + h6*sig2[b+6] + h7*sig2[b+7];
        }
    }
    __syncthreads();

    const float* down2 = buf;

    // ---- P4: out2 = (up4∘up2)(down2) ----
    {
        f4* __restrict__ out2_4 = (f4*)(outr + 2 * WT_L0);
        const int p = t & 1;                       // q parity (strides even)
        f4 wa, wb, wc;
        if (p == 0) {
            wa = (f4){0.4375f,  0.3125f,  0.21875f, 0.15625f};
            wb = (f4){0.5625f,  0.6875f,  0.75f,    0.75f   };
            wc = (f4){0.f,      0.f,      0.03125f, 0.09375f};
        } else {
            wa = (f4){0.09375f, 0.03125f, 0.f,      0.f     };
            wb = (f4){0.75f,    0.75f,    0.6875f,  0.5625f };
            wc = (f4){0.15625f, 0.21875f, 0.3125f,  0.4375f };
        }
        #pragma unroll
        for (int c = 0; c < 4; ++c) {
            int lq = t + WT_NT * c;                // 0..511
            int q  = 512 * h + lq;                 // global out2 f4 index
            int m  = q >> 1;                       // global down2 index
            int ld2 = (lq >> 1) + 1;               // m2(ld2) = m
            float d0 = down2[ld2];
            float dm = (m > 0)    ? down2[ld2 - 1] : d0;
            float dp = (m < 1023) ? down2[ld2 + 1] : d0;
            f4 o = wa * dm + wb * d0 + wc * dp;
            __builtin_nontemporal_store(o, &out2_4[q]);
        }
    }
}

extern "C" void kernel_launch(void* const* d_in, const int* in_sizes, int n_in,
                              void* d_out, int out_size, void* d_ws, size_t ws_size,
                              hipStream_t stream) {
    const float* x  = (const float*)d_in[0];
    const float* w0 = (const float*)d_in[1];
    const float* w1 = (const float*)d_in[2];
    const float* w2 = (const float*)d_in[3];
    float* out = (float*)d_out;

    const int rows = in_sizes[0] / WT_L0;     // B*C = 2048
    wavelet1d_kernel<<<dim3(rows * 4), dim3(WT_NT), 0, stream>>>(x, w0, w1, w2, out);
}

// Round 10
// 45.798 us; speedup vs baseline: 1.1630x; 1.1630x over previous
//
#include <hip/hip_runtime.h>

#define WT_L0 8192
#define WT_NT 256

typedef float f4 __attribute__((ext_vector_type(4)));
typedef float f2 __attribute__((ext_vector_type(2)));

// Each block does one HALF-row (4096 x-elements) with halo via sig1 staging.
// LDS floats (16.6 KB total):
//   sig1  [0,2072)     f2-cell j holds sig1 global pair g = 1024h-6+j   (0 when OOB)
//   down1 [2080,3108)  ld: gd = 1024h-2+ld
//   sig2  [3108,4144)  ls2: gs2 = 1024h-6+ls2
//   down2 [0,516)      (reuses sig1 region after it dies) ld2: gd2 = 512h-1+ld2
__global__ __launch_bounds__(WT_NT) void wavelet1d_kernel(
    const float* __restrict__ x,
    const float* __restrict__ w0,
    const float* __restrict__ w1,
    const float* __restrict__ w2,
    float* __restrict__ out)
{
    __shared__ float buf[4144];
    const int blk = blockIdx.x;
    const int row = blk >> 1;
    const int h   = blk & 1;
    const int t   = threadIdx.x;
    const float* __restrict__ xr = x + (size_t)row * WT_L0;
    float* __restrict__ outr = out + (size_t)row * 3 * WT_L0;

    float f0[3], f1[5], f2a[7];
    #pragma unroll
    for (int k = 0; k < 3; ++k) f0[k] = w0[k];
    #pragma unroll
    for (int k = 0; k < 5; ++k) f1[k] = w1[k];
    #pragma unroll
    for (int k = 0; k < 7; ++k) f2a[k] = w2[k];

    // composed pool∘conv5 (stride-2, 6 taps) and pool∘conv7 (stride-2, 8 taps)
    const float g0 = 0.5f*f1[0], g1 = 0.5f*(f1[0]+f1[1]), g2 = 0.5f*(f1[1]+f1[2]),
                g3 = 0.5f*(f1[2]+f1[3]), g4 = 0.5f*(f1[3]+f1[4]), g5 = 0.5f*f1[4];
    const float h0 = 0.5f*f2a[0], h1 = 0.5f*(f2a[0]+f2a[1]), h2 = 0.5f*(f2a[1]+f2a[2]),
                h3 = 0.5f*(f2a[2]+f2a[3]), h4 = 0.5f*(f2a[3]+f2a[4]),
                h5 = 0.5f*(f2a[4]+f2a[5]), h6 = 0.5f*(f2a[5]+f2a[6]), h7 = 0.5f*f2a[6];

    float* sig1  = buf;            // f2 cells [0,1036)
    float* down1 = buf + 2080;     // [0,1028)
    float* sig2  = buf + 3108;     // [0,1036)

    // ---- P1: stage sig1 (with halo, OOB=0) + conv3 -> out0 for own span ----
    {
        const f4* __restrict__ xr4 = (const f4*)xr;
        f4* __restrict__ out0_4 = (f4*)outr;
        f2* sig1_2 = (f2*)sig1;
        const int Gbase = 1024 * h - 6;
        for (int j = t; j < 1036; j += WT_NT) {
            const int G = Gbase + j;                 // global x f4 index
            f4 v = (G >= 0 && G < 2048) ? xr4[G] : (f4)(0.f);
            f2 s; s.x = 0.5f * (v.x + v.y); s.y = 0.5f * (v.z + v.w);
            sig1_2[j] = s;
            if (j >= 6 && j < 1030) {                // own span: G in [1024h, 1024h+1024)
                float lm = (G > 0)    ? xr[4 * G - 1] : 0.f;
                float rp = (G < 2047) ? xr[4 * G + 4] : 0.f;
                f4 o;
                o.x = f0[0]*lm  + f0[1]*v.x + f0[2]*v.y;
                o.y = f0[0]*v.x + f0[1]*v.y + f0[2]*v.z;
                o.z = f0[0]*v.y + f0[1]*v.z + f0[2]*v.w;
                o.w = f0[0]*v.z + f0[1]*v.w + f0[2]*rp;
                out0_4[G] = o;
            }
        }
    }
    __syncthreads();

    // ---- P2: down1 = (pool∘conv5)(sig1); sig2 = pool(sig1) ----
    {
        const f2* sig1_2 = (const f2*)sig1;
        #pragma unroll
        for (int c = 0; c < 5; ++c) {                // 1028 cells
            int ld = t + WT_NT * c;
            if (ld < 1028) {
                f2 a = sig1_2[ld + 3], b = sig1_2[ld + 4], cc = sig1_2[ld + 5];
                down1[ld] = g0*a.x + g1*a.y + g2*b.x + g3*b.y + g4*cc.x + g5*cc.y;
            }
        }
        #pragma unroll
        for (int c = 0; c < 5; ++c) {                // 1036 cells
            int ls2 = t + WT_NT * c;
            if (ls2 < 1036) {
                f2 p = ((const f2*)sig1)[ls2];
                sig2[ls2] = 0.5f * (p.x + p.y);
            }
        }
    }
    __syncthreads();

    // ---- P3: out1 = up2(up2(down1)); down2 = (pool∘conv7)(sig2) -> buf[0,516) ----
    {
        f4* __restrict__ out1_4 = (f4*)(outr + WT_L0);
        const int qbase = 1024 * h;
        #pragma unroll
        for (int c = 0; c < 4; ++c) {
            int lq = t + WT_NT * c;                  // 0..1023
            int q  = qbase + lq;                     // global down1/out1-f4 index
            int ld = lq + 2;
            float d0 = down1[ld];
            float dm = (q > 0)    ? down1[ld - 1] : d0;
            float dp = (q < 2047) ? down1[ld + 1] : d0;
            f4 o;
            o.x = 0.375f  * dm + 0.625f * d0;
            o.y = 0.1875f * dm + 0.75f  * d0 + 0.0625f * dp;
            o.z = 0.0625f * dm + 0.75f  * d0 + 0.1875f * dp;
            o.w = 0.625f  * d0 + 0.375f * dp;
            out1_4[q] = o;
        }
        float* down2 = buf;                          // sig1 dead
        #pragma unroll
        for (int c = 0; c < 3; ++c) {                // 514 cells
            int ld2 = t + WT_NT * c;
            if (ld2 < 514) {
                int b = 2 * ld2 + 1;                 // sig2 local base
                down2[ld2] = h0*sig2[b]   + h1*sig2[b+1] + h2*sig2[b+2] + h3*sig2[b+3]
                           + h4*sig2[b+4] + h5*sig2[b+5] + h6*sig2[b+6] + h7*sig2[b+7];
            }
        }
    }
    __syncthreads();

    const float* down2 = buf;

    // ---- P4: out2 = (up4∘up2)(down2) ----
    {
        f4* __restrict__ out2_4 = (f4*)(outr + 2 * WT_L0);
        const int p = t & 1;                         // parity, constant per thread
        f4 wa, wb, wc;
        if (p == 0) {
            wa = (f4){0.4375f,  0.3125f,  0.21875f, 0.15625f};
            wb = (f4){0.5625f,  0.6875f,  0.75f,    0.75f   };
            wc = (f4){0.f,      0.f,      0.03125f, 0.09375f};
        } else {
            wa = (f4){0.09375f, 0.03125f, 0.f,      0.f     };
            wb = (f4){0.75f,    0.75f,    0.6875f,  0.5625f };
            wc = (f4){0.15625f, 0.21875f, 0.3125f,  0.4375f };
        }
        #pragma unroll
        for (int c = 0; c < 4; ++c) {
            int lq = t + WT_NT * c;                  // 0..1023
            int q  = 1024 * h + lq;                  // global out2 f4 index
            int m  = q >> 1;                         // global down2 index
            int ld2 = (lq >> 1) + 1;
            float d0 = down2[ld2];
            float dm = (m > 0)    ? down2[ld2 - 1] : d0;
            float dp = (m < 1023) ? down2[ld2 + 1] : d0;
            f4 o = wa * dm + wb * d0 + wc * dp;
            out2_4[q] = o;
        }
    }
}

extern "C" void kernel_launch(void* const* d_in, const int* in_sizes, int n_in,
                              void* d_out, int out_size, void* d_ws, size_t ws_size,
                              hipStream_t stream) {
    const float* x  = (const float*)d_in[0];
    const float* w0 = (const float*)d_in[1];
    const float* w1 = (const float*)d_in[2];
    const float* w2 = (const float*)d_in[3];
    float* out = (float*)d_out;

    const int rows = in_sizes[0] / WT_L0;     // B*C = 2048
    wavelet1d_kernel<<<dim3(rows * 2), dim3(WT_NT), 0, stream>>>(x, w0, w1, w2, out);
}